// Round 24
// baseline (457.790 us; speedup 1.0000x reference)
//
#include <hip/hip_runtime.h>
#include <stdint.h>

typedef __attribute__((ext_vector_type(8))) _Float16 half8;
typedef __attribute__((ext_vector_type(4))) float f32x4;

#define CDIM 256
#define KCODES 1024
#define NPTS 131072
#define ZQ_ELEMS 33554432u
#define CAP 32768
#define MARGIN 3.0e-4f

// ws layout (bytes)
#define WS_IMG 0
#define WS_S2 (16 * 65536)
#define WS_IDX (WS_S2 + 4096)
#define WS_PART (WS_IDX + NPTS * 4)
#define WS_CNT (WS_PART + 65536)
#define WS_LIST (WS_CNT + 64)

__device__ __forceinline__ float np_pairwise_sq_256(const float* x) {
    float res[2];
#pragma unroll
    for (int h = 0; h < 2; h++) {
        const float* a = x + h * 128;
        float r[8];
#pragma unroll
        for (int j = 0; j < 8; j++) r[j] = __fmul_rn(a[j], a[j]);
#pragma unroll
        for (int i = 8; i < 128; i += 8)
#pragma unroll
            for (int j = 0; j < 8; j++)
                r[j] = __fadd_rn(r[j], __fmul_rn(a[i + j], a[i + j]));
        res[h] = __fadd_rn(__fadd_rn(__fadd_rn(r[0], r[1]), __fadd_rn(r[2], r[3])),
                           __fadd_rn(__fadd_rn(r[4], r[5]), __fadd_rn(r[6], r[7])));
    }
    return __fadd_rn(res[0], res[1]);
}

// ---------------- fused prep: img fragments + s2 (32 codes/block, 32 blocks) --------
__global__ __launch_bounds__(256) void vq_prepall(const float* __restrict__ cb,
                                                  unsigned char* __restrict__ img,
                                                  float* __restrict__ s2,
                                                  int* __restrict__ cnt) {
    __shared__ float rows[32 * 261];
    int t = threadIdx.x;
    int k0 = blockIdx.x * 32;
    if (blockIdx.x == 0 && t == 0) *cnt = 0;
#pragma unroll
    for (int i = 0; i < 8; i++) {
        int u = i * 256 + t;
        int row = u >> 6, c4 = u & 63;
        float4 v = *(const float4*)&cb[(size_t)(k0 + row) * CDIM + c4 * 4];
        float* d = &rows[row * 261 + c4 * 4];
        d[0] = v.x; d[1] = v.y; d[2] = v.z; d[3] = v.w;
    }
    __syncthreads();
    if (t < 32) s2[k0 + t] = np_pairwise_sq_256(&rows[t * 261]);
#pragma unroll
    for (int i = 0; i < 4; i++) {
        int u = i * 256 + t;
        int cl = u >> 5, cg = u & 31;
        union H { _Float16 h[8]; uint4 u4; } hv;
#pragma unroll
        for (int j = 0; j < 8; j++) hv.h[j] = (_Float16)(rows[cl * 261 + cg * 8 + j] * 1024.f);
        int ks = cg >> 2, l4 = cg & 3;
        int q = cl >> 4, l15 = cl & 15;
        int lane = l4 * 16 + l15;
        *(uint4*)(img + (size_t)blockIdx.x * 16384 + ((ks * 2 + q) << 10) + lane * 16) = hv.u4;
    }
}

// ---------------- pass 1 (r23 core) + fused z_q/index write epilogue ----------------
__global__ __launch_bounds__(256, 2) void vq_dist(const float* __restrict__ z,
                                                  const unsigned char* __restrict__ img,
                                                  const float* __restrict__ s2g,
                                                  const float* __restrict__ cb,
                                                  int* __restrict__ outIdx,
                                                  int* __restrict__ cnt,
                                                  int* __restrict__ list,
                                                  float* __restrict__ partial,
                                                  float* __restrict__ out) {
    __shared__ __align__(16) unsigned char smem[3][16384];
    __shared__ float e2s[1024];
    __shared__ float lred[4];
    __shared__ int idxl[256];
    int t = threadIdx.x;
    int lane = t & 63, wave = t >> 6;
    int l15 = lane & 15, l4 = lane >> 4;
    int blk0 = blockIdx.x * 256;
    int wbase = blk0 + wave * 64;
    int b = blk0 >> 12;
    int hwb0 = blk0 & 4095;
    const float* zb = z + (size_t)b * (CDIM * 4096);
    unsigned char* sbase = &smem[0][0];

#pragma unroll
    for (int i = 0; i < 4; i++) e2s[t + i * 256] = s2g[t + i * 256];

    half8 aHi[4][8];
    float s1p[4] = {0.f, 0.f, 0.f, 0.f};
#pragma unroll
    for (int ks = 0; ks < 8; ks++) {
        __syncthreads();
#pragma unroll
        for (int i = 0; i < 8; i++) {
            int u = i * 256 + t;
            int row = u >> 6, col16 = u & 63;
            const float* gsrc = zb + (size_t)(ks * 32 + row) * 4096 + hwb0 + col16 * 4;
            __builtin_amdgcn_global_load_lds(
                (const __attribute__((address_space(1))) void*)gsrc,
                (__attribute__((address_space(3))) void*)(sbase + (size_t)u * 16), 16, 0, 0);
        }
        __syncthreads();
#pragma unroll
        for (int m = 0; m < 4; m++) {
            half8 h;
            float ss = s1p[m];
#pragma unroll
            for (int j = 0; j < 8; j++) {
                float f = *(const float*)(sbase +
                        (size_t)(((l4 * 8 + j) << 8) + wave * 64 + m * 16 + l15) * 4) * 32.f;
                h[j] = (_Float16)f;
                ss = fmaf(f, f, ss);
            }
            aHi[m][ks] = h;
            s1p[m] = ss;
        }
    }
    __syncthreads();
#pragma unroll
    for (int m = 0; m < 4; m++) {
        s1p[m] += __shfl_xor(s1p[m], 16);
        s1p[m] += __shfl_xor(s1p[m], 32);
    }

#pragma unroll
    for (int i = 0; i < 4; i++) {
        size_t off = (size_t)(i * 256 + t) * 16;
        __builtin_amdgcn_global_load_lds(
            (const __attribute__((address_space(1))) void*)(img + off),
            (__attribute__((address_space(3))) void*)(&smem[0][0] + off), 16, 0, 0);
    }
#pragma unroll
    for (int i = 0; i < 4; i++) {
        size_t off = (size_t)(i * 256 + t) * 16;
        __builtin_amdgcn_global_load_lds(
            (const __attribute__((address_space(1))) void*)(img + 16384 + off),
            (__attribute__((address_space(3))) void*)(&smem[1][0] + off), 16, 0, 0);
    }

    float bestv[4][4], bestv2[4][4];
    int besti[4][4];
#pragma unroll
    for (int m = 0; m < 4; m++)
#pragma unroll
        for (int j = 0; j < 4; j++) { bestv[m][j] = 3.0e38f; bestv2[m][j] = 3.0e38f; besti[m][j] = 0; }

    int i0 = 0, i1 = 1, i2 = 2;
    for (int chunk = 0; chunk < 32; chunk++) {
        if (chunk < 31) asm volatile("s_waitcnt vmcnt(4)" ::: "memory");
        else            asm volatile("s_waitcnt vmcnt(0)" ::: "memory");
        __builtin_amdgcn_s_barrier();

        if (chunk + 2 < 32) {
            const unsigned char* src = img + (size_t)(chunk + 2) * 16384;
            unsigned char* dst = &smem[0][0] + (size_t)i2 * 16384;
#pragma unroll
            for (int i = 0; i < 4; i++) {
                size_t off = (size_t)(i * 256 + t) * 16;
                __builtin_amdgcn_global_load_lds(
                    (const __attribute__((address_space(1))) void*)(src + off),
                    (__attribute__((address_space(3))) void*)(dst + off), 16, 0, 0);
            }
        }

        f32x4 acc[4][2];
#pragma unroll
        for (int m = 0; m < 4; m++)
#pragma unroll
            for (int q = 0; q < 2; q++) acc[m][q] = (f32x4){0.f, 0.f, 0.f, 0.f};

        const unsigned char* bufc = &smem[0][0] + (size_t)i0 * 16384 + lane * 16;
#pragma unroll
        for (int ks = 0; ks < 8; ks++) {
            half8 b0 = *(const half8*)(bufc + (ks << 11));
            half8 b1 = *(const half8*)(bufc + (ks << 11) + 1024);
#pragma unroll
            for (int m = 0; m < 4; m++) {
                acc[m][0] = __builtin_amdgcn_mfma_f32_16x16x32_f16(aHi[m][ks], b0, acc[m][0], 0, 0, 0);
                acc[m][1] = __builtin_amdgcn_mfma_f32_16x16x32_f16(aHi[m][ks], b1, acc[m][1], 0, 0, 0);
            }
        }
#pragma unroll
        for (int q = 0; q < 2; q++) {
            int code = chunk * 32 + q * 16 + l15;
            float ev = e2s[code];
#pragma unroll
            for (int m = 0; m < 4; m++)
#pragma unroll
                for (int j = 0; j < 4; j++) {
                    float s = fmaf(acc[m][q][j], -6.103515625e-05f, ev);
                    if (s < bestv[m][j]) { bestv2[m][j] = bestv[m][j]; bestv[m][j] = s; besti[m][j] = code; }
                    else if (s < bestv2[m][j]) bestv2[m][j] = s;
                }
        }
        int tmp = i0; i0 = i1; i1 = i2; i2 = tmp;
    }

    float lsum = 0.f;
#pragma unroll
    for (int m = 0; m < 4; m++)
#pragma unroll
        for (int j = 0; j < 4; j++) {
            float v = bestv[m][j], v2 = bestv2[m][j];
            int idx = besti[m][j];
#pragma unroll
            for (int off = 1; off < 16; off <<= 1) {
                float ov = __shfl_xor(v, off);
                float ov2 = __shfl_xor(v2, off);
                int oi = __shfl_xor(idx, off);
                if (ov < v || (ov == v && oi < idx)) { v2 = fminf(v, ov2); v = ov; idx = oi; }
                else v2 = fminf(v2, ov);
            }
            int r = l4 * 4 + j;
            float S1r = __shfl(s1p[m], r) * 9.765625e-4f;   // /1024 (f = 32z)
            if (l15 == 0) {
                lsum += S1r + v;
                int pl = wave * 64 + m * 16 + l4 * 4 + j;
                idxl[pl] = idx;
                int p = blk0 + pl;
                outIdx[p] = idx;
                if (v2 - v < MARGIN) {
                    int pos = atomicAdd(cnt, 1);
                    if (pos < CAP) list[pos] = p;
                }
            }
        }

    // ---- fused z_q + index writes (pass-1 indices; rescue fixes changed points) ----
    __syncthreads();   // idxl visible; all K-loop LDS readers done
    out[(size_t)ZQ_ELEMS + 1u + blk0 + t] = (float)idxl[t];   // indices, 1KB coalesced
    int myid = idxl[t];
    float* tile = (float*)&smem[0][0];   // 32KB [32ch][256hw] tile
#pragma unroll 1
    for (int s = 0; s < 8; s++) {
        const float4* crow = (const float4*)(cb + (size_t)myid * CDIM + s * 32);
#pragma unroll
        for (int i = 0; i < 8; i++) {
            float4 v = crow[i];
            int c = i * 4;
            tile[(c + 0) * 256 + t] = v.x;
            tile[(c + 1) * 256 + t] = v.y;
            tile[(c + 2) * 256 + t] = v.z;
            tile[(c + 3) * 256 + t] = v.w;
        }
        __syncthreads();
#pragma unroll
        for (int i = 0; i < 8; i++) {
            int u = i * 256 + t;
            int row = u >> 6, col4 = u & 63;
            float4 v = *(const float4*)&tile[row * 256 + col4 * 4];
            *(float4*)&out[(((size_t)(b * 256 + s * 32 + row)) << 12) + hwb0 + col4 * 4] = v;
        }
        __syncthreads();   // tile free for next slice
    }

    // block-reduce provisional loss
#pragma unroll
    for (int off = 32; off > 0; off >>= 1) lsum += __shfl_down(lsum, off);
    if (lane == 0) lred[wave] = lsum;
    __syncthreads();
    if (t == 0) partial[blockIdx.x] = lred[0] + lred[1] + lred[2] + lred[3];
}

// ---------------- rescue v2: np-exact rescore, direct cb reads, z_q/index fixup ----------
__global__ __launch_bounds__(256) void vq_rescue(const float* __restrict__ z,
                                                 const float* __restrict__ cb,
                                                 const float* __restrict__ s2,
                                                 const int* __restrict__ list,
                                                 const int* __restrict__ cnt,
                                                 int* __restrict__ outIdx,
                                                 float* __restrict__ out) {
    __shared__ float zs[8][256];
    __shared__ float S1s[8];
    __shared__ float rv[256];
    __shared__ int ri[256];
    __shared__ int newbest;
    int n = *cnt; if (n > CAP) n = CAP;
    int t = threadIdx.x;
    for (int base = blockIdx.x * 8; base < n; base += gridDim.x * 8) {
        int npts = n - base; if (npts > 8) npts = 8;
        __syncthreads();
        {
            int pp = t >> 5, c0 = (t & 31) * 8;
            if (pp < npts) {
                int p = list[base + pp];
                int b = p >> 12, hw = p & 4095;
                const float* zp = z + ((size_t)b << 20) + hw;
#pragma unroll
                for (int j = 0; j < 8; j++) zs[pp][c0 + j] = zp[(size_t)(c0 + j) << 12];
            }
        }
        __syncthreads();
        if (t < npts) S1s[t] = np_pairwise_sq_256(zs[t]);
        __syncthreads();

        // per-thread codes {t, 256+t, 512+t, 768+t}; c-ascending fma chains (bit-exact)
        float d[8][4];
#pragma unroll
        for (int pp = 0; pp < 8; pp++)
#pragma unroll
            for (int q = 0; q < 4; q++) d[pp][q] = 0.f;
        for (int c4 = 0; c4 < 64; c4++) {
            float4 e[4];
#pragma unroll
            for (int q = 0; q < 4; q++)
                e[q] = *(const float4*)&cb[(size_t)(q * 256 + t) * CDIM + c4 * 4];
#pragma unroll
            for (int pp = 0; pp < 8; pp++) {
                float z0 = zs[pp][c4 * 4 + 0], z1 = zs[pp][c4 * 4 + 1];
                float z2 = zs[pp][c4 * 4 + 2], z3 = zs[pp][c4 * 4 + 3];
#pragma unroll
                for (int q = 0; q < 4; q++) {
                    d[pp][q] = fmaf(z0, e[q].x, d[pp][q]);
                    d[pp][q] = fmaf(z1, e[q].y, d[pp][q]);
                    d[pp][q] = fmaf(z2, e[q].z, d[pp][q]);
                    d[pp][q] = fmaf(z3, e[q].w, d[pp][q]);
                }
            }
        }
        float s2v[4] = {s2[t], s2[256 + t], s2[512 + t], s2[768 + t]};

        float bv[8]; int bi[8];
#pragma unroll
        for (int pp = 0; pp < 8; pp++) {
            float v = 3.4e38f; int i0 = 0;
#pragma unroll
            for (int q = 0; q < 4; q++) {
                float dist = __fsub_rn(__fadd_rn(S1s[pp], s2v[q]), __fmul_rn(2.0f, d[pp][q]));
                if (dist < v) { v = dist; i0 = q * 256 + t; }
            }
            bv[pp] = v; bi[pp] = i0;
        }
        for (int pp = 0; pp < 8; pp++) {
            if (pp >= npts) break;
            rv[t] = bv[pp]; ri[t] = bi[pp];
            __syncthreads();
            for (int sft = 128; sft > 0; sft >>= 1) {
                if (t < sft) {
                    if (rv[t + sft] < rv[t] || (rv[t + sft] == rv[t] && ri[t + sft] < ri[t])) {
                        rv[t] = rv[t + sft]; ri[t] = ri[t + sft];
                    }
                }
                __syncthreads();
            }
            int p = list[base + pp];
            if (t == 0) {
                int old = outIdx[p];
                newbest = (ri[0] != old) ? ri[0] : -1;
                if (ri[0] != old) {
                    outIdx[p] = ri[0];
                    out[(size_t)ZQ_ELEMS + 1u + p] = (float)ri[0];
                }
            }
            __syncthreads();
            int nb = newbest;
            if (nb >= 0) {   // fix z_q row for changed point (256 scattered 4B stores)
                int b = p >> 12, hw = p & 4095;
                out[(((size_t)(b * 256 + t)) << 12) + hw] = cb[(size_t)nb * CDIM + t];
            }
            __syncthreads();
        }
    }
}

__global__ __launch_bounds__(512) void vq_finalize(const float* __restrict__ partial,
                                                   float* __restrict__ out) {
    int t = threadIdx.x;
    double s = (double)partial[t];
#pragma unroll
    for (int off = 32; off > 0; off >>= 1) s += __shfl_down(s, off);
    __shared__ double sd[8];
    if ((t & 63) == 0) sd[t >> 6] = s;
    __syncthreads();
    if (t == 0) {
        double tot = sd[0] + sd[1] + sd[2] + sd[3] + sd[4] + sd[5] + sd[6] + sd[7];
        out[ZQ_ELEMS] = (float)(1.25 * tot / (double)ZQ_ELEMS);
    }
}

extern "C" void kernel_launch(void* const* d_in, const int* in_sizes, int n_in,
                              void* d_out, int out_size, void* d_ws, size_t ws_size,
                              hipStream_t stream) {
    const float* z = (const float*)d_in[0];
    const float* cb = (const float*)d_in[1];
    unsigned char* ws = (unsigned char*)d_ws;
    unsigned char* img = ws + WS_IMG;
    float* s2 = (float*)(ws + WS_S2);
    int* idx = (int*)(ws + WS_IDX);
    float* partial = (float*)(ws + WS_PART);
    int* cnt = (int*)(ws + WS_CNT);
    int* list = (int*)(ws + WS_LIST);
    float* out = (float*)d_out;

    vq_prepall<<<32, 256, 0, stream>>>(cb, img, s2, cnt);
    vq_dist<<<512, 256, 0, stream>>>(z, img, s2, cb, idx, cnt, list, partial, out);
    vq_rescue<<<1024, 256, 0, stream>>>(z, cb, s2, list, cnt, idx, out);
    vq_finalize<<<1, 512, 0, stream>>>(partial, out);
}

// Round 25
// 316.557 us; speedup vs baseline: 1.4462x; 1.4462x over previous
//
#include <hip/hip_runtime.h>
#include <stdint.h>

typedef __attribute__((ext_vector_type(8))) _Float16 half8;
typedef __attribute__((ext_vector_type(4))) float f32x4;

#define CDIM 256
#define KCODES 1024
#define NPTS 131072
#define ZQ_ELEMS 33554432u
#define CAP 32768
#define MARGIN 3.0e-4f

// ws layout (bytes): img 512K | cbT 1M | s2 4K | partial 2K | cnt 64 | list 128K  (~1.67MB)
#define WS_IMG 0
#define WS_CBT (512 * 1024)
#define WS_S2 (WS_CBT + 1024 * 1024)
#define WS_PART (WS_S2 + 4096)
#define WS_CNT (WS_PART + 2048)
#define WS_LIST (WS_CNT + 64)

__device__ __forceinline__ float np_pairwise_sq_256(const float* x) {
    float res[2];
#pragma unroll
    for (int h = 0; h < 2; h++) {
        const float* a = x + h * 128;
        float r[8];
#pragma unroll
        for (int j = 0; j < 8; j++) r[j] = __fmul_rn(a[j], a[j]);
#pragma unroll
        for (int i = 8; i < 128; i += 8)
#pragma unroll
            for (int j = 0; j < 8; j++)
                r[j] = __fadd_rn(r[j], __fmul_rn(a[i + j], a[i + j]));
        res[h] = __fadd_rn(__fadd_rn(__fadd_rn(r[0], r[1]), __fadd_rn(r[2], r[3])),
                           __fadd_rn(__fadd_rn(r[4], r[5]), __fadd_rn(r[6], r[7])));
    }
    return __fadd_rn(res[0], res[1]);
}

// ---------------- fused prep: img fragments + s2 + cbT (32 codes/block, 32 blocks) --------
__global__ __launch_bounds__(256) void vq_prepall(const float* __restrict__ cb,
                                                  unsigned char* __restrict__ img,
                                                  float* __restrict__ s2,
                                                  float* __restrict__ cbT,
                                                  int* __restrict__ cnt) {
    __shared__ float rows[32 * 261];
    int t = threadIdx.x;
    int k0 = blockIdx.x * 32;
    if (blockIdx.x == 0 && t == 0) *cnt = 0;
#pragma unroll
    for (int i = 0; i < 8; i++) {
        int u = i * 256 + t;
        int row = u >> 6, c4 = u & 63;
        float4 v = *(const float4*)&cb[(size_t)(k0 + row) * CDIM + c4 * 4];
        float* d = &rows[row * 261 + c4 * 4];
        d[0] = v.x; d[1] = v.y; d[2] = v.z; d[3] = v.w;
    }
    __syncthreads();
    if (t < 32) s2[k0 + t] = np_pairwise_sq_256(&rows[t * 261]);
#pragma unroll
    for (int i = 0; i < 4; i++) {
        int u = i * 256 + t;
        int cl = u >> 5, cg = u & 31;
        union H { _Float16 h[8]; uint4 u4; } hv;
#pragma unroll
        for (int j = 0; j < 8; j++) hv.h[j] = (_Float16)(rows[cl * 261 + cg * 8 + j] * 1024.f);
        int ks = cg >> 2, l4 = cg & 3;
        int q = cl >> 4, l15 = cl & 15;
        int lane = l4 * 16 + l15;
        *(uint4*)(img + (size_t)blockIdx.x * 16384 + ((ks * 2 + q) << 10) + lane * 16) = hv.u4;
    }
    // cbT[c][k0+row] (coalesced in k across threads of same c)
#pragma unroll
    for (int i = 0; i < 32; i++) {
        int u = i * 256 + t;
        int c = u >> 5, row = u & 31;
        cbT[(size_t)c * 1024 + k0 + row] = rows[row * 261 + c];
    }
}

// ---------------- pass 1 (r24 core, fused z_q/index writes; outIdx store dropped) ----------
__global__ __launch_bounds__(256, 2) void vq_dist(const float* __restrict__ z,
                                                  const unsigned char* __restrict__ img,
                                                  const float* __restrict__ s2g,
                                                  const float* __restrict__ cb,
                                                  int* __restrict__ cnt,
                                                  int* __restrict__ list,
                                                  float* __restrict__ partial,
                                                  float* __restrict__ out) {
    __shared__ __align__(16) unsigned char smem[3][16384];
    __shared__ float e2s[1024];
    __shared__ float lred[4];
    __shared__ int idxl[256];
    int t = threadIdx.x;
    int lane = t & 63, wave = t >> 6;
    int l15 = lane & 15, l4 = lane >> 4;
    int blk0 = blockIdx.x * 256;
    int b = blk0 >> 12;
    int hwb0 = blk0 & 4095;
    const float* zb = z + (size_t)b * (CDIM * 4096);
    unsigned char* sbase = &smem[0][0];

#pragma unroll
    for (int i = 0; i < 4; i++) e2s[t + i * 256] = s2g[t + i * 256];

    half8 aHi[4][8];
    float s1p[4] = {0.f, 0.f, 0.f, 0.f};
#pragma unroll
    for (int ks = 0; ks < 8; ks++) {
        __syncthreads();
#pragma unroll
        for (int i = 0; i < 8; i++) {
            int u = i * 256 + t;
            int row = u >> 6, col16 = u & 63;
            const float* gsrc = zb + (size_t)(ks * 32 + row) * 4096 + hwb0 + col16 * 4;
            __builtin_amdgcn_global_load_lds(
                (const __attribute__((address_space(1))) void*)gsrc,
                (__attribute__((address_space(3))) void*)(sbase + (size_t)u * 16), 16, 0, 0);
        }
        __syncthreads();
#pragma unroll
        for (int m = 0; m < 4; m++) {
            half8 h;
            float ss = s1p[m];
#pragma unroll
            for (int j = 0; j < 8; j++) {
                float f = *(const float*)(sbase +
                        (size_t)(((l4 * 8 + j) << 8) + wave * 64 + m * 16 + l15) * 4) * 32.f;
                h[j] = (_Float16)f;
                ss = fmaf(f, f, ss);
            }
            aHi[m][ks] = h;
            s1p[m] = ss;
        }
    }
    __syncthreads();
#pragma unroll
    for (int m = 0; m < 4; m++) {
        s1p[m] += __shfl_xor(s1p[m], 16);
        s1p[m] += __shfl_xor(s1p[m], 32);
    }

#pragma unroll
    for (int i = 0; i < 4; i++) {
        size_t off = (size_t)(i * 256 + t) * 16;
        __builtin_amdgcn_global_load_lds(
            (const __attribute__((address_space(1))) void*)(img + off),
            (__attribute__((address_space(3))) void*)(&smem[0][0] + off), 16, 0, 0);
    }
#pragma unroll
    for (int i = 0; i < 4; i++) {
        size_t off = (size_t)(i * 256 + t) * 16;
        __builtin_amdgcn_global_load_lds(
            (const __attribute__((address_space(1))) void*)(img + 16384 + off),
            (__attribute__((address_space(3))) void*)(&smem[1][0] + off), 16, 0, 0);
    }

    float bestv[4][4], bestv2[4][4];
    int besti[4][4];
#pragma unroll
    for (int m = 0; m < 4; m++)
#pragma unroll
        for (int j = 0; j < 4; j++) { bestv[m][j] = 3.0e38f; bestv2[m][j] = 3.0e38f; besti[m][j] = 0; }

    int i0 = 0, i1 = 1, i2 = 2;
    for (int chunk = 0; chunk < 32; chunk++) {
        if (chunk < 31) asm volatile("s_waitcnt vmcnt(4)" ::: "memory");
        else            asm volatile("s_waitcnt vmcnt(0)" ::: "memory");
        __builtin_amdgcn_s_barrier();

        if (chunk + 2 < 32) {
            const unsigned char* src = img + (size_t)(chunk + 2) * 16384;
            unsigned char* dst = &smem[0][0] + (size_t)i2 * 16384;
#pragma unroll
            for (int i = 0; i < 4; i++) {
                size_t off = (size_t)(i * 256 + t) * 16;
                __builtin_amdgcn_global_load_lds(
                    (const __attribute__((address_space(1))) void*)(src + off),
                    (__attribute__((address_space(3))) void*)(dst + off), 16, 0, 0);
            }
        }

        f32x4 acc[4][2];
#pragma unroll
        for (int m = 0; m < 4; m++)
#pragma unroll
            for (int q = 0; q < 2; q++) acc[m][q] = (f32x4){0.f, 0.f, 0.f, 0.f};

        const unsigned char* bufc = &smem[0][0] + (size_t)i0 * 16384 + lane * 16;
#pragma unroll
        for (int ks = 0; ks < 8; ks++) {
            half8 b0 = *(const half8*)(bufc + (ks << 11));
            half8 b1 = *(const half8*)(bufc + (ks << 11) + 1024);
#pragma unroll
            for (int m = 0; m < 4; m++) {
                acc[m][0] = __builtin_amdgcn_mfma_f32_16x16x32_f16(aHi[m][ks], b0, acc[m][0], 0, 0, 0);
                acc[m][1] = __builtin_amdgcn_mfma_f32_16x16x32_f16(aHi[m][ks], b1, acc[m][1], 0, 0, 0);
            }
        }
#pragma unroll
        for (int q = 0; q < 2; q++) {
            int code = chunk * 32 + q * 16 + l15;
            float ev = e2s[code];
#pragma unroll
            for (int m = 0; m < 4; m++)
#pragma unroll
                for (int j = 0; j < 4; j++) {
                    float s = fmaf(acc[m][q][j], -6.103515625e-05f, ev);
                    if (s < bestv[m][j]) { bestv2[m][j] = bestv[m][j]; bestv[m][j] = s; besti[m][j] = code; }
                    else if (s < bestv2[m][j]) bestv2[m][j] = s;
                }
        }
        int tmp = i0; i0 = i1; i1 = i2; i2 = tmp;
    }

    float lsum = 0.f;
#pragma unroll
    for (int m = 0; m < 4; m++)
#pragma unroll
        for (int j = 0; j < 4; j++) {
            float v = bestv[m][j], v2 = bestv2[m][j];
            int idx = besti[m][j];
#pragma unroll
            for (int off = 1; off < 16; off <<= 1) {
                float ov = __shfl_xor(v, off);
                float ov2 = __shfl_xor(v2, off);
                int oi = __shfl_xor(idx, off);
                if (ov < v || (ov == v && oi < idx)) { v2 = fminf(v, ov2); v = ov; idx = oi; }
                else v2 = fminf(v2, ov);
            }
            int r = l4 * 4 + j;
            float S1r = __shfl(s1p[m], r) * 9.765625e-4f;   // /1024 (f = 32z)
            if (l15 == 0) {
                lsum += S1r + v;
                int pl = wave * 64 + m * 16 + l4 * 4 + j;
                idxl[pl] = idx;
                if (v2 - v < MARGIN) {
                    int pos = atomicAdd(cnt, 1);
                    if (pos < CAP) list[pos] = blk0 + pl;
                }
            }
        }

    // ---- fused z_q + index writes (pass-1 indices; rescue fixes changed points) ----
    __syncthreads();   // idxl visible; all K-loop LDS readers done
    out[(size_t)ZQ_ELEMS + 1u + blk0 + t] = (float)idxl[t];   // indices, 1KB coalesced
    int myid = idxl[t];
    float* tile = (float*)&smem[0][0];   // 32KB [32ch][256hw] tile
#pragma unroll 1
    for (int s = 0; s < 8; s++) {
        const float4* crow = (const float4*)(cb + (size_t)myid * CDIM + s * 32);
#pragma unroll
        for (int i = 0; i < 8; i++) {
            float4 v = crow[i];
            int c = i * 4;
            tile[(c + 0) * 256 + t] = v.x;
            tile[(c + 1) * 256 + t] = v.y;
            tile[(c + 2) * 256 + t] = v.z;
            tile[(c + 3) * 256 + t] = v.w;
        }
        __syncthreads();
#pragma unroll
        for (int i = 0; i < 8; i++) {
            int u = i * 256 + t;
            int row = u >> 6, col4 = u & 63;
            float4 v = *(const float4*)&tile[row * 256 + col4 * 4];
            *(float4*)&out[(((size_t)(b * 256 + s * 32 + row)) << 12) + hwb0 + col4 * 4] = v;
        }
        __syncthreads();   // tile free for next slice
    }

    // block-reduce provisional loss
#pragma unroll
    for (int off = 32; off > 0; off >>= 1) lsum += __shfl_down(lsum, off);
    if (lane == 0) lred[wave] = lsum;
    __syncthreads();
    if (t == 0) partial[blockIdx.x] = lred[0] + lred[1] + lred[2] + lred[3];
}

// ---------------- rescue v4: r23's coalesced-cbT np-exact rescore + out fixup ----------
__global__ __launch_bounds__(256) void vq_rescue(const float* __restrict__ z,
                                                 const float* __restrict__ cbT,
                                                 const float* __restrict__ cb,
                                                 const float* __restrict__ s2,
                                                 const int* __restrict__ list,
                                                 const int* __restrict__ cnt,
                                                 float* __restrict__ out) {
    __shared__ float zs[8][256];
    __shared__ float S1s[8];
    __shared__ float rv[256];
    __shared__ int ri[256];
    __shared__ int newbest;
    int n = *cnt; if (n > CAP) n = CAP;
    int t = threadIdx.x;
    for (int base = blockIdx.x * 8; base < n; base += gridDim.x * 8) {
        int npts = n - base; if (npts > 8) npts = 8;
        __syncthreads();
        {
            int pp = t >> 5, c0 = (t & 31) * 8;
            if (pp < npts) {
                int p = list[base + pp];
                int b = p >> 12, hw = p & 4095;
                const float* zp = z + ((size_t)b << 20) + hw;
#pragma unroll
                for (int j = 0; j < 8; j++) zs[pp][c0 + j] = zp[(size_t)(c0 + j) << 12];
            }
        }
        __syncthreads();
        if (t < npts) S1s[t] = np_pairwise_sq_256(zs[t]);
        __syncthreads();

        float d[8][4];
#pragma unroll
        for (int pp = 0; pp < 8; pp++)
#pragma unroll
            for (int q = 0; q < 4; q++) d[pp][q] = 0.f;
        for (int c = 0; c < 256; c++) {
            const float* er = cbT + c * 1024 + t;
            float e0 = er[0], e1 = er[256], e2v = er[512], e3 = er[768];
#pragma unroll
            for (int pp = 0; pp < 8; pp++) {
                float zc = zs[pp][c];
                d[pp][0] = fmaf(zc, e0, d[pp][0]);
                d[pp][1] = fmaf(zc, e1, d[pp][1]);
                d[pp][2] = fmaf(zc, e2v, d[pp][2]);
                d[pp][3] = fmaf(zc, e3, d[pp][3]);
            }
        }
        float s2v[4] = {s2[t], s2[256 + t], s2[512 + t], s2[768 + t]};

        float bv[8]; int bi[8];
#pragma unroll
        for (int pp = 0; pp < 8; pp++) {
            float v = 3.4e38f; int i0 = 0;
#pragma unroll
            for (int q = 0; q < 4; q++) {
                float dist = __fsub_rn(__fadd_rn(S1s[pp], s2v[q]), __fmul_rn(2.0f, d[pp][q]));
                if (dist < v) { v = dist; i0 = q * 256 + t; }
            }
            bv[pp] = v; bi[pp] = i0;
        }
        for (int pp = 0; pp < 8; pp++) {
            if (pp >= npts) break;
            rv[t] = bv[pp]; ri[t] = bi[pp];
            __syncthreads();
            for (int sft = 128; sft > 0; sft >>= 1) {
                if (t < sft) {
                    if (rv[t + sft] < rv[t] || (rv[t + sft] == rv[t] && ri[t + sft] < ri[t])) {
                        rv[t] = rv[t + sft]; ri[t] = ri[t + sft];
                    }
                }
                __syncthreads();
            }
            int p = list[base + pp];
            if (t == 0) {
                int old = (int)out[(size_t)ZQ_ELEMS + 1u + p];
                newbest = (ri[0] != old) ? ri[0] : -1;
                if (ri[0] != old)
                    out[(size_t)ZQ_ELEMS + 1u + p] = (float)ri[0];
            }
            __syncthreads();
            int nb = newbest;
            if (nb >= 0) {   // fix z_q row for changed point (rare)
                int b = p >> 12, hw = p & 4095;
                out[(((size_t)(b * 256 + t)) << 12) + hw] = cb[(size_t)nb * CDIM + t];
            }
            __syncthreads();
        }
    }
}

__global__ __launch_bounds__(512) void vq_finalize(const float* __restrict__ partial,
                                                   float* __restrict__ out) {
    int t = threadIdx.x;
    double s = (double)partial[t];
#pragma unroll
    for (int off = 32; off > 0; off >>= 1) s += __shfl_down(s, off);
    __shared__ double sd[8];
    if ((t & 63) == 0) sd[t >> 6] = s;
    __syncthreads();
    if (t == 0) {
        double tot = sd[0] + sd[1] + sd[2] + sd[3] + sd[4] + sd[5] + sd[6] + sd[7];
        out[ZQ_ELEMS] = (float)(1.25 * tot / (double)ZQ_ELEMS);
    }
}

extern "C" void kernel_launch(void* const* d_in, const int* in_sizes, int n_in,
                              void* d_out, int out_size, void* d_ws, size_t ws_size,
                              hipStream_t stream) {
    const float* z = (const float*)d_in[0];
    const float* cb = (const float*)d_in[1];
    unsigned char* ws = (unsigned char*)d_ws;
    unsigned char* img = ws + WS_IMG;
    float* cbT = (float*)(ws + WS_CBT);
    float* s2 = (float*)(ws + WS_S2);
    float* partial = (float*)(ws + WS_PART);
    int* cnt = (int*)(ws + WS_CNT);
    int* list = (int*)(ws + WS_LIST);
    float* out = (float*)d_out;

    vq_prepall<<<32, 256, 0, stream>>>(cb, img, s2, cbT, cnt);
    vq_dist<<<512, 256, 0, stream>>>(z, img, s2, cb, cnt, list, partial, out);
    vq_rescue<<<1024, 256, 0, stream>>>(z, cbT, cb, s2, list, cnt, out);
    vq_finalize<<<1, 512, 0, stream>>>(partial, out);
}

// Round 26
// 309.334 us; speedup vs baseline: 1.4799x; 1.0233x over previous
//
#include <hip/hip_runtime.h>
#include <stdint.h>

typedef __attribute__((ext_vector_type(8))) _Float16 half8;
typedef __attribute__((ext_vector_type(4))) float f32x4;

#define CDIM 256
#define KCODES 1024
#define NPTS 131072
#define ZQ_ELEMS 33554432u
#define CAP 32768
#define MARGIN 3.0e-4f

// ws layout (bytes): img 512K | cbT 1M | s2 4K | partial 2K | cnt 64 | list 128K  (~1.67MB)
#define WS_IMG 0
#define WS_CBT (512 * 1024)
#define WS_S2 (WS_CBT + 1024 * 1024)
#define WS_PART (WS_S2 + 4096)
#define WS_CNT (WS_PART + 2048)
#define WS_LIST (WS_CNT + 64)

__device__ __forceinline__ float np_pairwise_sq_256(const float* x) {
    float res[2];
#pragma unroll
    for (int h = 0; h < 2; h++) {
        const float* a = x + h * 128;
        float r[8];
#pragma unroll
        for (int j = 0; j < 8; j++) r[j] = __fmul_rn(a[j], a[j]);
#pragma unroll
        for (int i = 8; i < 128; i += 8)
#pragma unroll
            for (int j = 0; j < 8; j++)
                r[j] = __fadd_rn(r[j], __fmul_rn(a[i + j], a[i + j]));
        res[h] = __fadd_rn(__fadd_rn(__fadd_rn(r[0], r[1]), __fadd_rn(r[2], r[3])),
                           __fadd_rn(__fadd_rn(r[4], r[5]), __fadd_rn(r[6], r[7])));
    }
    return __fadd_rn(res[0], res[1]);
}

// ---------------- fused prep: img fragments + s2 + cbT (32 codes/block, 32 blocks) --------
__global__ __launch_bounds__(256) void vq_prepall(const float* __restrict__ cb,
                                                  unsigned char* __restrict__ img,
                                                  float* __restrict__ s2,
                                                  float* __restrict__ cbT,
                                                  int* __restrict__ cnt) {
    __shared__ float rows[32 * 261];
    int t = threadIdx.x;
    int k0 = blockIdx.x * 32;
    if (blockIdx.x == 0 && t == 0) *cnt = 0;
#pragma unroll
    for (int i = 0; i < 8; i++) {
        int u = i * 256 + t;
        int row = u >> 6, c4 = u & 63;
        float4 v = *(const float4*)&cb[(size_t)(k0 + row) * CDIM + c4 * 4];
        float* d = &rows[row * 261 + c4 * 4];
        d[0] = v.x; d[1] = v.y; d[2] = v.z; d[3] = v.w;
    }
    __syncthreads();
    if (t < 32) s2[k0 + t] = np_pairwise_sq_256(&rows[t * 261]);
#pragma unroll
    for (int i = 0; i < 4; i++) {
        int u = i * 256 + t;
        int cl = u >> 5, cg = u & 31;
        union H { _Float16 h[8]; uint4 u4; } hv;
#pragma unroll
        for (int j = 0; j < 8; j++) hv.h[j] = (_Float16)(rows[cl * 261 + cg * 8 + j] * 1024.f);
        int ks = cg >> 2, l4 = cg & 3;
        int q = cl >> 4, l15 = cl & 15;
        int lane = l4 * 16 + l15;
        *(uint4*)(img + (size_t)blockIdx.x * 16384 + ((ks * 2 + q) << 10) + lane * 16) = hv.u4;
    }
#pragma unroll
    for (int i = 0; i < 32; i++) {
        int u = i * 256 + t;
        int c = u >> 5, row = u & 31;
        cbT[(size_t)c * 1024 + k0 + row] = rows[row * 261 + c];
    }
}

// ---------------- pass 1 (r25, verified passing; byte-identical) ----------------
__global__ __launch_bounds__(256, 2) void vq_dist(const float* __restrict__ z,
                                                  const unsigned char* __restrict__ img,
                                                  const float* __restrict__ s2g,
                                                  const float* __restrict__ cb,
                                                  int* __restrict__ cnt,
                                                  int* __restrict__ list,
                                                  float* __restrict__ partial,
                                                  float* __restrict__ out) {
    __shared__ __align__(16) unsigned char smem[3][16384];
    __shared__ float e2s[1024];
    __shared__ float lred[4];
    __shared__ int idxl[256];
    int t = threadIdx.x;
    int lane = t & 63, wave = t >> 6;
    int l15 = lane & 15, l4 = lane >> 4;
    int blk0 = blockIdx.x * 256;
    int b = blk0 >> 12;
    int hwb0 = blk0 & 4095;
    const float* zb = z + (size_t)b * (CDIM * 4096);
    unsigned char* sbase = &smem[0][0];

#pragma unroll
    for (int i = 0; i < 4; i++) e2s[t + i * 256] = s2g[t + i * 256];

    half8 aHi[4][8];
    float s1p[4] = {0.f, 0.f, 0.f, 0.f};
#pragma unroll
    for (int ks = 0; ks < 8; ks++) {
        __syncthreads();
#pragma unroll
        for (int i = 0; i < 8; i++) {
            int u = i * 256 + t;
            int row = u >> 6, col16 = u & 63;
            const float* gsrc = zb + (size_t)(ks * 32 + row) * 4096 + hwb0 + col16 * 4;
            __builtin_amdgcn_global_load_lds(
                (const __attribute__((address_space(1))) void*)gsrc,
                (__attribute__((address_space(3))) void*)(sbase + (size_t)u * 16), 16, 0, 0);
        }
        __syncthreads();
#pragma unroll
        for (int m = 0; m < 4; m++) {
            half8 h;
            float ss = s1p[m];
#pragma unroll
            for (int j = 0; j < 8; j++) {
                float f = *(const float*)(sbase +
                        (size_t)(((l4 * 8 + j) << 8) + wave * 64 + m * 16 + l15) * 4) * 32.f;
                h[j] = (_Float16)f;
                ss = fmaf(f, f, ss);
            }
            aHi[m][ks] = h;
            s1p[m] = ss;
        }
    }
    __syncthreads();
#pragma unroll
    for (int m = 0; m < 4; m++) {
        s1p[m] += __shfl_xor(s1p[m], 16);
        s1p[m] += __shfl_xor(s1p[m], 32);
    }

#pragma unroll
    for (int i = 0; i < 4; i++) {
        size_t off = (size_t)(i * 256 + t) * 16;
        __builtin_amdgcn_global_load_lds(
            (const __attribute__((address_space(1))) void*)(img + off),
            (__attribute__((address_space(3))) void*)(&smem[0][0] + off), 16, 0, 0);
    }
#pragma unroll
    for (int i = 0; i < 4; i++) {
        size_t off = (size_t)(i * 256 + t) * 16;
        __builtin_amdgcn_global_load_lds(
            (const __attribute__((address_space(1))) void*)(img + 16384 + off),
            (__attribute__((address_space(3))) void*)(&smem[1][0] + off), 16, 0, 0);
    }

    float bestv[4][4], bestv2[4][4];
    int besti[4][4];
#pragma unroll
    for (int m = 0; m < 4; m++)
#pragma unroll
        for (int j = 0; j < 4; j++) { bestv[m][j] = 3.0e38f; bestv2[m][j] = 3.0e38f; besti[m][j] = 0; }

    int i0 = 0, i1 = 1, i2 = 2;
    for (int chunk = 0; chunk < 32; chunk++) {
        if (chunk < 31) asm volatile("s_waitcnt vmcnt(4)" ::: "memory");
        else            asm volatile("s_waitcnt vmcnt(0)" ::: "memory");
        __builtin_amdgcn_s_barrier();

        if (chunk + 2 < 32) {
            const unsigned char* src = img + (size_t)(chunk + 2) * 16384;
            unsigned char* dst = &smem[0][0] + (size_t)i2 * 16384;
#pragma unroll
            for (int i = 0; i < 4; i++) {
                size_t off = (size_t)(i * 256 + t) * 16;
                __builtin_amdgcn_global_load_lds(
                    (const __attribute__((address_space(1))) void*)(src + off),
                    (__attribute__((address_space(3))) void*)(dst + off), 16, 0, 0);
            }
        }

        f32x4 acc[4][2];
#pragma unroll
        for (int m = 0; m < 4; m++)
#pragma unroll
            for (int q = 0; q < 2; q++) acc[m][q] = (f32x4){0.f, 0.f, 0.f, 0.f};

        const unsigned char* bufc = &smem[0][0] + (size_t)i0 * 16384 + lane * 16;
#pragma unroll
        for (int ks = 0; ks < 8; ks++) {
            half8 b0 = *(const half8*)(bufc + (ks << 11));
            half8 b1 = *(const half8*)(bufc + (ks << 11) + 1024);
#pragma unroll
            for (int m = 0; m < 4; m++) {
                acc[m][0] = __builtin_amdgcn_mfma_f32_16x16x32_f16(aHi[m][ks], b0, acc[m][0], 0, 0, 0);
                acc[m][1] = __builtin_amdgcn_mfma_f32_16x16x32_f16(aHi[m][ks], b1, acc[m][1], 0, 0, 0);
            }
        }
#pragma unroll
        for (int q = 0; q < 2; q++) {
            int code = chunk * 32 + q * 16 + l15;
            float ev = e2s[code];
#pragma unroll
            for (int m = 0; m < 4; m++)
#pragma unroll
                for (int j = 0; j < 4; j++) {
                    float s = fmaf(acc[m][q][j], -6.103515625e-05f, ev);
                    if (s < bestv[m][j]) { bestv2[m][j] = bestv[m][j]; bestv[m][j] = s; besti[m][j] = code; }
                    else if (s < bestv2[m][j]) bestv2[m][j] = s;
                }
        }
        int tmp = i0; i0 = i1; i1 = i2; i2 = tmp;
    }

    float lsum = 0.f;
#pragma unroll
    for (int m = 0; m < 4; m++)
#pragma unroll
        for (int j = 0; j < 4; j++) {
            float v = bestv[m][j], v2 = bestv2[m][j];
            int idx = besti[m][j];
#pragma unroll
            for (int off = 1; off < 16; off <<= 1) {
                float ov = __shfl_xor(v, off);
                float ov2 = __shfl_xor(v2, off);
                int oi = __shfl_xor(idx, off);
                if (ov < v || (ov == v && oi < idx)) { v2 = fminf(v, ov2); v = ov; idx = oi; }
                else v2 = fminf(v2, ov);
            }
            int r = l4 * 4 + j;
            float S1r = __shfl(s1p[m], r) * 9.765625e-4f;   // /1024 (f = 32z)
            if (l15 == 0) {
                lsum += S1r + v;
                int pl = wave * 64 + m * 16 + l4 * 4 + j;
                idxl[pl] = idx;
                if (v2 - v < MARGIN) {
                    int pos = atomicAdd(cnt, 1);
                    if (pos < CAP) list[pos] = blk0 + pl;
                }
            }
        }

    // ---- fused z_q + index writes (pass-1 indices; rescue fixes changed points) ----
    __syncthreads();
    out[(size_t)ZQ_ELEMS + 1u + blk0 + t] = (float)idxl[t];
    int myid = idxl[t];
    float* tile = (float*)&smem[0][0];
#pragma unroll 1
    for (int s = 0; s < 8; s++) {
        const float4* crow = (const float4*)(cb + (size_t)myid * CDIM + s * 32);
#pragma unroll
        for (int i = 0; i < 8; i++) {
            float4 v = crow[i];
            int c = i * 4;
            tile[(c + 0) * 256 + t] = v.x;
            tile[(c + 1) * 256 + t] = v.y;
            tile[(c + 2) * 256 + t] = v.z;
            tile[(c + 3) * 256 + t] = v.w;
        }
        __syncthreads();
#pragma unroll
        for (int i = 0; i < 8; i++) {
            int u = i * 256 + t;
            int row = u >> 6, col4 = u & 63;
            float4 v = *(const float4*)&tile[row * 256 + col4 * 4];
            *(float4*)&out[(((size_t)(b * 256 + s * 32 + row)) << 12) + hwb0 + col4 * 4] = v;
        }
        __syncthreads();
    }

#pragma unroll
    for (int off = 32; off > 0; off >>= 1) lsum += __shfl_down(lsum, off);
    if (lane == 0) lred[wave] = lsum;
    __syncthreads();
    if (t == 0) partial[blockIdx.x] = lred[0] + lred[1] + lred[2] + lred[3];
}

// ---------------- rescue v5: wave-shuffle argmin (2 barriers/batch), single-pass grid ------
__global__ __launch_bounds__(256) void vq_rescue(const float* __restrict__ z,
                                                 const float* __restrict__ cbT,
                                                 const float* __restrict__ cb,
                                                 const float* __restrict__ s2,
                                                 const int* __restrict__ list,
                                                 const int* __restrict__ cnt,
                                                 float* __restrict__ out) {
    __shared__ float zs[8][256];
    __shared__ float S1s[8];
    __shared__ float wv[8][4];
    __shared__ int wi[8][4];
    int n = *cnt; if (n > CAP) n = CAP;
    int t = threadIdx.x;
    int lane = t & 63, wave = t >> 6;
    for (int base = blockIdx.x * 8; base < n; base += gridDim.x * 8) {
        int npts = n - base; if (npts > 8) npts = 8;
        __syncthreads();
        {
            int pp = t >> 5, c0 = (t & 31) * 8;
            if (pp < npts) {
                int p = list[base + pp];
                int b = p >> 12, hw = p & 4095;
                const float* zp = z + ((size_t)b << 20) + hw;
#pragma unroll
                for (int j = 0; j < 8; j++) zs[pp][c0 + j] = zp[(size_t)(c0 + j) << 12];
            }
        }
        __syncthreads();
        if (t < npts) S1s[t] = np_pairwise_sq_256(zs[t]);
        __syncthreads();

        float d[8][4];
#pragma unroll
        for (int pp = 0; pp < 8; pp++)
#pragma unroll
            for (int q = 0; q < 4; q++) d[pp][q] = 0.f;
        for (int c = 0; c < 256; c++) {
            const float* er = cbT + c * 1024 + t;
            float e0 = er[0], e1 = er[256], e2v = er[512], e3 = er[768];
#pragma unroll
            for (int pp = 0; pp < 8; pp++) {
                float zc = zs[pp][c];
                d[pp][0] = fmaf(zc, e0, d[pp][0]);
                d[pp][1] = fmaf(zc, e1, d[pp][1]);
                d[pp][2] = fmaf(zc, e2v, d[pp][2]);
                d[pp][3] = fmaf(zc, e3, d[pp][3]);
            }
        }
        float s2v[4] = {s2[t], s2[256 + t], s2[512 + t], s2[768 + t]};

        // per-point wave-level argmin (6 shfl steps, no barrier)
#pragma unroll
        for (int pp = 0; pp < 8; pp++) {
            float v = 3.4e38f; int idx = 0;
#pragma unroll
            for (int q = 0; q < 4; q++) {
                float dist = __fsub_rn(__fadd_rn(S1s[pp], s2v[q]), __fmul_rn(2.0f, d[pp][q]));
                if (dist < v) { v = dist; idx = q * 256 + t; }
            }
#pragma unroll
            for (int off = 1; off < 64; off <<= 1) {
                float ov = __shfl_xor(v, off);
                int oi = __shfl_xor(idx, off);
                if (ov < v || (ov == v && oi < idx)) { v = ov; idx = oi; }
            }
            if (lane == 0) { wv[pp][wave] = v; wi[pp][wave] = idx; }
        }
        __syncthreads();

        // combine 4 wave winners redundantly in every thread; barrier-free fixup
        for (int pp = 0; pp < npts; pp++) {
            float fv = wv[pp][0]; int fi = wi[pp][0];
#pragma unroll
            for (int w = 1; w < 4; w++) {
                float ov = wv[pp][w]; int oi = wi[pp][w];
                if (ov < fv || (ov == fv && oi < fi)) { fv = ov; fi = oi; }
            }
            int p = list[base + pp];
            int old = (int)out[(size_t)ZQ_ELEMS + 1u + p];
            if (fi != old) {
                int b = p >> 12, hw = p & 4095;
                out[(((size_t)(b * 256 + t)) << 12) + hw] = cb[(size_t)fi * CDIM + t];
                if (t == 0) out[(size_t)ZQ_ELEMS + 1u + p] = (float)fi;
            }
        }
        __syncthreads();   // zs/wv reuse safe for next batch
    }
}

__global__ __launch_bounds__(512) void vq_finalize(const float* __restrict__ partial,
                                                   float* __restrict__ out) {
    int t = threadIdx.x;
    double s = (double)partial[t];
#pragma unroll
    for (int off = 32; off > 0; off >>= 1) s += __shfl_down(s, off);
    __shared__ double sd[8];
    if ((t & 63) == 0) sd[t >> 6] = s;
    __syncthreads();
    if (t == 0) {
        double tot = sd[0] + sd[1] + sd[2] + sd[3] + sd[4] + sd[5] + sd[6] + sd[7];
        out[ZQ_ELEMS] = (float)(1.25 * tot / (double)ZQ_ELEMS);
    }
}

extern "C" void kernel_launch(void* const* d_in, const int* in_sizes, int n_in,
                              void* d_out, int out_size, void* d_ws, size_t ws_size,
                              hipStream_t stream) {
    const float* z = (const float*)d_in[0];
    const float* cb = (const float*)d_in[1];
    unsigned char* ws = (unsigned char*)d_ws;
    unsigned char* img = ws + WS_IMG;
    float* cbT = (float*)(ws + WS_CBT);
    float* s2 = (float*)(ws + WS_S2);
    float* partial = (float*)(ws + WS_PART);
    int* cnt = (int*)(ws + WS_CNT);
    int* list = (int*)(ws + WS_LIST);
    float* out = (float*)d_out;

    vq_prepall<<<32, 256, 0, stream>>>(cb, img, s2, cbT, cnt);
    vq_dist<<<512, 256, 0, stream>>>(z, img, s2, cb, cnt, list, partial, out);
    vq_rescue<<<2048, 256, 0, stream>>>(z, cbT, cb, s2, list, cnt, out);
    vq_finalize<<<1, 512, 0, stream>>>(partial, out);
}